// Round 16
// baseline (43.639 us; speedup 1.0000x reference)
//
#include <hip/hip_runtime.h>
#include <math.h>

#define MARGIN 0.3f
#define NJG 8        // column groups (grid.y); group = 1024 cols = 4 chunks of 256

typedef short bf16x8 __attribute__((ext_vector_type(8)));
typedef float f32x4 __attribute__((ext_vector_type(4)));
typedef unsigned int u32;
typedef const __attribute__((address_space(1))) u32* gp_t;
typedef __attribute__((address_space(3))) u32* lp_t;

__device__ __forceinline__ unsigned short f2bf_rne(float x) {
    unsigned b = __float_as_uint(x);
    unsigned r = b + 0x7FFFu + ((b >> 16) & 1u);
    return (unsigned short)(r >> 16);
}
// family table {0,1,2,1,3,3} packed 2 bits/entry
__device__ __forceinline__ int fam_of(int lbl) { return (0xF64 >> (2 * lbl)) & 3; }

// ---------------- K1: fused sort + normalize + pack (verified R14/R15) ----------------
__global__ __launch_bounds__(256) void prep_kernel(
    const float* __restrict__ emb, const int* __restrict__ labels,
    unsigned char* __restrict__ famSorted, int* __restrict__ famLoHi,
    unsigned* __restrict__ counters, short* __restrict__ pack, int B) {
    __shared__ int wt[4][4];
    __shared__ int posL[32];
    const int t = threadIdx.x, lane = t & 63, wid = t >> 6, bid = blockIdx.x;

    unsigned long long lfp = 0ull;
    int lc0 = 0, lc1 = 0, lc2 = 0, lc3 = 0;
#pragma unroll
    for (int j = 0; j < 32; j++) {
        int f = fam_of(labels[t * 32 + j]);
        lfp |= (unsigned long long)f << (2 * j);
        lc0 += (f == 0); lc1 += (f == 1); lc2 += (f == 2); lc3 += (f == 3);
    }
    int i0 = lc0, i1 = lc1, i2 = lc2, i3 = lc3;
#pragma unroll
    for (int o = 1; o < 64; o <<= 1) {
        int u0 = __shfl_up(i0, o, 64), u1 = __shfl_up(i1, o, 64);
        int u2 = __shfl_up(i2, o, 64), u3 = __shfl_up(i3, o, 64);
        if (lane >= o) { i0 += u0; i1 += u1; i2 += u2; i3 += u3; }
    }
    if (lane == 63) { wt[wid][0] = i0; wt[wid][1] = i1; wt[wid][2] = i2; wt[wid][3] = i3; }
    __syncthreads();
    int wb0 = 0, wb1 = 0, wb2 = 0, wb3 = 0, to0 = 0, to1 = 0, to2 = 0, to3 = 0;
#pragma unroll
    for (int w2 = 0; w2 < 4; w2++) {
        int v0 = wt[w2][0], v1 = wt[w2][1], v2 = wt[w2][2], v3 = wt[w2][3];
        if (w2 < wid) { wb0 += v0; wb1 += v1; wb2 += v2; wb3 += v3; }
        to0 += v0; to1 += v1; to2 += v2; to3 += v3;
    }
    const int fb0 = 0, fb1 = to0, fb2 = to0 + to1, fb3 = to0 + to1 + to2;
    if (bid == 0 && t == 0) {
        famLoHi[0] = fb0; famLoHi[1] = fb1; famLoHi[2] = fb2; famLoHi[3] = fb3;
        famLoHi[4] = fb1; famLoHi[5] = fb2; famLoHi[6] = fb3; famLoHi[7] = fb3 + to3;
        counters[0] = 0;   // re-armed every call
    }
    int b0 = fb0 + wb0 + (i0 - lc0);
    int b1 = fb1 + wb1 + (i1 - lc1);
    int b2 = fb2 + wb2 + (i2 - lc2);
    int b3 = fb3 + wb3 + (i3 - lc3);
#pragma unroll
    for (int j = 0; j < 32; j++) {
        int f = (int)((lfp >> (2 * j)) & 3ull);
        int pos = (f == 0) ? b0 : ((f == 1) ? b1 : ((f == 2) ? b2 : b3));
        if (bid == 0) famSorted[pos] = (unsigned char)f;
        if (t == bid) posL[j] = pos;
        b0 += (f == 0); b1 += (f == 1); b2 += (f == 2); b3 += (f == 3);
    }
    __syncthreads();
#pragma unroll
    for (int rep = 0; rep < 8; rep++) {
        int rl = rep * 4 + wid;
        float x = emb[(size_t)(bid * 32 + rl) * 64 + lane];
        float ss = x * x;
#pragma unroll
        for (int o = 32; o > 0; o >>= 1) ss += __shfl_xor(ss, o, 64);
        unsigned short h = f2bf_rne(x / fmaxf(sqrtf(ss), 1e-12f));
        int pos = posL[rl];
        size_t idx = (size_t)(pos >> 4) * 1024 + (size_t)(lane >> 3) * 128 +
                     (size_t)(pos & 15) * 8 + (lane & 7);
        pack[idx] = (short)h;
    }
}

// ---------------- K2: long-block GEMM: 4 chunks/block, double-buffered LDS ----------------
// Grid 256 (32 row-blocks x 8 col-groups) = 1 block/CU. Block: 256 rows x 1024
// cols (4 chunks of 256). A fragments loaded ONCE; per chunk, stage next chunk's
// 32KB into the other LDS buffer while computing (1 barrier/chunk). Inner loop
// body identical to R11's proven codegen (swapped operands, lane-local min/max).
__global__ __launch_bounds__(256) void gemm_minmax_kernel(
    const short* __restrict__ pack,
    const unsigned char* __restrict__ famSorted, const int* __restrict__ famLoHi,
    float* __restrict__ pMin, float* __restrict__ pMax, int B) {
    __shared__ short ldsB[32768];   // 2 x 32 KB double buffer

    const int lane = threadIdx.x & 63;
    const int wid  = threadIdx.x >> 6;
    const int g = lane >> 4;
    const int c = lane & 15;
    const int rowBase = blockIdx.x * 256 + wid * 64;
    const int aStrip0 = rowBase >> 4;
    const int colGroup = blockIdx.y;
    const int jGroup0 = colGroup * 1024;

    // A (row) fragments: 4 strips x 2 k-windows = 32 VGPRs, resident all sweep.
    bf16x8 aH[4][2];
#pragma unroll
    for (int s = 0; s < 4; s++) {
        const short* pA = pack + (size_t)(aStrip0 + s) * 1024;
        aH[s][0] = *(const bf16x8*)(pA + lane * 8);
        aH[s][1] = *(const bf16x8*)(pA + 512 + lane * 8);
    }

    // Stage chunk 0 into buffer 0: 32 KB linear; each wave 8 x 1KB.
    {
        const char* src = (const char*)(pack + (size_t)(jGroup0 >> 4) * 1024);
#pragma unroll
        for (int i = 0; i < 8; i++) {
            int off = wid * 8192 + i * 1024;
            __builtin_amdgcn_global_load_lds((gp_t)(src + off + lane * 16),
                                             (lp_t)((char*)ldsB + off), 16, 0, 0);
        }
    }

    // Per-strip family classification (rows sorted -> piecewise constant).
    int sLo[4], sHi[4], sUni[4];
#pragma unroll
    for (int s = 0; s < 4; s++) {
        int f0  = famSorted[rowBase + s * 16];
        int f15 = famSorted[rowBase + s * 16 + 15];
        sUni[s] = __builtin_amdgcn_readfirstlane((f0 == f15) ? 1 : 0);
        sLo[s]  = __builtin_amdgcn_readfirstlane(famLoHi[f0]);
        sHi[s]  = __builtin_amdgcn_readfirstlane(famLoHi[4 + f0]);
    }

    const f32x4 zq = {0.f, 0.f, 0.f, 0.f};
    float mn[4] = {1e30f, 1e30f, 1e30f, 1e30f};
    float mx[4] = {-1e30f, -1e30f, -1e30f, -1e30f};

    __syncthreads();   // chunk-0 staging drained (compiler emits vmcnt(0) before barrier)

    for (int ch = 0; ch < 4; ch++) {        // runtime loop: compact code, 4 chunks
        const int jChunk0 = jGroup0 + ch * 256;
        const char* bufC = (char*)ldsB + (ch & 1) * 32768;
        // issue next chunk's staging into the other buffer (drains at loop-end barrier)
        if (ch < 3) {
            const char* src = (const char*)(pack + (size_t)((jChunk0 + 256) >> 4) * 1024);
            const char* dst = (char*)ldsB + ((ch + 1) & 1) * 32768;
#pragma unroll
            for (int i = 0; i < 8; i++) {
                int off = wid * 8192 + i * 1024;
                __builtin_amdgcn_global_load_lds((gp_t)(src + off + lane * 16),
                                                 (lp_t)(dst + off), 16, 0, 0);
            }
        }

#pragma unroll
        for (int jp = 0; jp < 8; jp++) {
            const int j0 = jChunk0 + jp * 32;
            const short* pB0 = (const short*)bufC + (size_t)(2 * jp) * 1024;
            const short* pB1 = pB0 + 1024;
            bf16x8 b0h0 = *(const bf16x8*)(pB0 + lane * 8);
            bf16x8 b0h1 = *(const bf16x8*)(pB0 + 512 + lane * 8);
            bf16x8 b1h0 = *(const bf16x8*)(pB1 + lane * 8);
            bf16x8 b1h1 = *(const bf16x8*)(pB1 + 512 + lane * 8);

#pragma unroll
            for (int s = 0; s < 4; s++) {
                // swapped operands: D[j][i], j=(g,reg) cols, i=lane&15 row
                f32x4 accA, accB;
                accA = __builtin_amdgcn_mfma_f32_16x16x32_bf16(b0h0, aH[s][0], zq, 0, 0, 0);
                accB = __builtin_amdgcn_mfma_f32_16x16x32_bf16(b1h0, aH[s][0], zq, 0, 0, 0);
                accA = __builtin_amdgcn_mfma_f32_16x16x32_bf16(b0h1, aH[s][1], accA, 0, 0, 0);
                accB = __builtin_amdgcn_mfma_f32_16x16x32_bf16(b1h1, aH[s][1], accB, 0, 0, 0);

                if (sUni[s] && j0 >= sLo[s] && j0 + 32 <= sHi[s]) {
                    // both tiles fully same-family (diag dot~1 never the min)
                    float a01 = fminf(accA[0], accA[1]), a23 = fminf(accA[2], accA[3]);
                    float b01 = fminf(accB[0], accB[1]), b23 = fminf(accB[2], accB[3]);
                    mn[s] = fminf(mn[s], fminf(fminf(a01, a23), fminf(b01, b23)));
                } else if (sUni[s] && (j0 >= sHi[s] || j0 + 32 <= sLo[s])) {
                    // both tiles fully different-family
                    float a01 = fmaxf(accA[0], accA[1]), a23 = fmaxf(accA[2], accA[3]);
                    float b01 = fmaxf(accB[0], accB[1]), b23 = fmaxf(accB[2], accB[3]);
                    mx[s] = fmaxf(mx[s], fmaxf(fmaxf(a01, a23), fmaxf(b01, b23)));
                } else {
                    // rare: pair spans a family boundary -> per-element compare
                    int fi = famSorted[rowBase + s * 16 + c];
                    unsigned fjA = *(const unsigned*)(famSorted + j0 + g * 4);
                    unsigned fjB = *(const unsigned*)(famSorted + j0 + 16 + g * 4);
#pragma unroll
                    for (int r = 0; r < 4; r++) {
                        bool sameA = ((int)((fjA >> (8 * r)) & 255u) == fi);
                        bool sameB = ((int)((fjB >> (8 * r)) & 255u) == fi);
                        mn[s] = fminf(mn[s], sameA ? accA[r] : 1e30f);
                        mx[s] = fmaxf(mx[s], sameA ? -1e30f : accA[r]);
                        mn[s] = fminf(mn[s], sameB ? accB[r] : 1e30f);
                        mx[s] = fmaxf(mx[s], sameB ? -1e30f : accB[r]);
                    }
                }
            }
        }
        __syncthreads();   // drains next-chunk staging; LDS reads done before reuse
    }

    // Reduce across the 4 g-groups (lanes c, c+16, c+32, c+48): 2 shfl rounds.
#pragma unroll
    for (int s = 0; s < 4; s++) {
        float mnv = mn[s], mxv = mx[s];
        mnv = fminf(mnv, __shfl_xor(mnv, 16, 64));
        mxv = fmaxf(mxv, __shfl_xor(mxv, 16, 64));
        mnv = fminf(mnv, __shfl_xor(mnv, 32, 64));
        mxv = fmaxf(mxv, __shfl_xor(mxv, 32, 64));
        if (g == 0) {
            int row = rowBase + s * 16 + c;  // sorted-row index; 16-lane coalesced
            pMin[(size_t)colGroup * B + row] = mnv;
            pMax[(size_t)colGroup * B + row] = mxv;
        }
    }
}

// ---------------- K3: per-row combine + partial sums + last-block finalize ----------------
__global__ __launch_bounds__(256) void rowloss_final_kernel(const float* __restrict__ pMin,
                                                            const float* __restrict__ pMax,
                                                            float* __restrict__ partial,
                                                            unsigned* __restrict__ counter,
                                                            float* __restrict__ out, int B) {
    const int nb = B / 256;  // 32 blocks
    const int row = blockIdx.x * 256 + threadIdx.x;
    float mn = 1e30f, mx = -1e30f;
#pragma unroll
    for (int cn = 0; cn < NJG; cn++) {
        mn = fminf(mn, pMin[(size_t)cn * B + row]);
        mx = fmaxf(mx, pMax[(size_t)cn * B + row]);
    }
    float sum = 0.f, cnt = 0.f;
    if (mn < 1e29f && mx > -1e29f) {  // has same && has diff
        sum = fmaxf(mx - mn + MARGIN, 0.f);  // relu(d_pos - d_neg + margin)
        cnt = 1.f;
    }
#pragma unroll
    for (int o = 32; o > 0; o >>= 1) {
        sum += __shfl_xor(sum, o, 64);
        cnt += __shfl_xor(cnt, o, 64);
    }
    __shared__ float sS[4], sC[4];
    const int lane = threadIdx.x & 63, w = threadIdx.x >> 6;
    if (lane == 0) { sS[w] = sum; sC[w] = cnt; }
    __syncthreads();
    if (threadIdx.x == 0) {
        partial[blockIdx.x]      = sS[0] + sS[1] + sS[2] + sS[3];
        partial[64 + blockIdx.x] = sC[0] + sC[1] + sC[2] + sC[3];
        __threadfence();
        unsigned done = atomicAdd(counter, 1u);
        if (done == (unsigned)(nb - 1)) {   // last block finalizes
            __threadfence();
            float S = 0.f, C = 0.f;
            for (int i = 0; i < nb; i++) { S += partial[i]; C += partial[64 + i]; }
            out[0] = S / fmaxf(C, 1.f);
        }
    }
}

extern "C" void kernel_launch(void* const* d_in, const int* in_sizes, int n_in,
                              void* d_out, int out_size, void* d_ws, size_t ws_size,
                              hipStream_t stream) {
    const float* emb    = (const float*)d_in[0];
    const int*   labels = (const int*)d_in[1];
    const int B = in_sizes[1];  // 8192, D == 64

    char* base = (char*)d_ws;
    size_t off = 0;
    auto alloc = [&](size_t bytes) -> char* {
        char* p = base + off;
        off = (off + bytes + 255) & ~(size_t)255;
        return p;
    };
    unsigned char* famSorted = (unsigned char*)alloc((size_t)B);
    int*           famLoHi   = (int*)alloc(64);
    unsigned*      counters  = (unsigned*)alloc(64);
    short*         pack      = (short*)alloc((size_t)B * 64 * 2);  // hi-only, 1MB
    float*         pMin      = (float*)alloc((size_t)NJG * B * 4);
    float*         pMax      = (float*)alloc((size_t)NJG * B * 4);
    float*         partial   = (float*)alloc(128 * 4);

    prep_kernel<<<256, 256, 0, stream>>>(emb, labels, famSorted, famLoHi,
                                         counters, pack, B);
    dim3 g3(B / 256, NJG);
    gemm_minmax_kernel<<<g3, 256, 0, stream>>>(pack, famSorted, famLoHi, pMin, pMax, B);
    rowloss_final_kernel<<<B / 256, 256, 0, stream>>>(pMin, pMax, partial, counters,
                                                      (float*)d_out, B);
}

// Round 17
// 35.302 us; speedup vs baseline: 1.2362x; 1.2362x over previous
//
#include <hip/hip_runtime.h>
#include <math.h>

#define MARGIN 0.3f
#define NJ 64        // column chunks; chunk = 128 cols = 4 pairs of 16x2
#define NPAIR 4      // (8192/NJ)/32

typedef short bf16x8 __attribute__((ext_vector_type(8)));
typedef float f32x4 __attribute__((ext_vector_type(4)));
typedef unsigned int u32;
typedef const __attribute__((address_space(1))) u32* gp_t;
typedef __attribute__((address_space(3))) u32* lp_t;

__device__ __forceinline__ unsigned short f2bf_rne(float x) {
    unsigned b = __float_as_uint(x);
    unsigned r = b + 0x7FFFu + ((b >> 16) & 1u);
    return (unsigned short)(r >> 16);
}
// family table {0,1,2,1,3,3} packed 2 bits/entry
__device__ __forceinline__ int fam_of(int lbl) { return (0xF64 >> (2 * lbl)) & 3; }

// ---------------- K1: fused sort + normalize + pack (verified R14/R15) ----------------
__global__ __launch_bounds__(256) void prep_kernel(
    const float* __restrict__ emb, const int* __restrict__ labels,
    unsigned char* __restrict__ famSorted, int* __restrict__ famLoHi,
    unsigned* __restrict__ counters, short* __restrict__ pack, int B) {
    __shared__ int wt[4][4];
    __shared__ int posL[32];
    const int t = threadIdx.x, lane = t & 63, wid = t >> 6, bid = blockIdx.x;

    unsigned long long lfp = 0ull;
    int lc0 = 0, lc1 = 0, lc2 = 0, lc3 = 0;
#pragma unroll
    for (int j = 0; j < 32; j++) {
        int f = fam_of(labels[t * 32 + j]);
        lfp |= (unsigned long long)f << (2 * j);
        lc0 += (f == 0); lc1 += (f == 1); lc2 += (f == 2); lc3 += (f == 3);
    }
    int i0 = lc0, i1 = lc1, i2 = lc2, i3 = lc3;
#pragma unroll
    for (int o = 1; o < 64; o <<= 1) {
        int u0 = __shfl_up(i0, o, 64), u1 = __shfl_up(i1, o, 64);
        int u2 = __shfl_up(i2, o, 64), u3 = __shfl_up(i3, o, 64);
        if (lane >= o) { i0 += u0; i1 += u1; i2 += u2; i3 += u3; }
    }
    if (lane == 63) { wt[wid][0] = i0; wt[wid][1] = i1; wt[wid][2] = i2; wt[wid][3] = i3; }
    __syncthreads();
    int wb0 = 0, wb1 = 0, wb2 = 0, wb3 = 0, to0 = 0, to1 = 0, to2 = 0, to3 = 0;
#pragma unroll
    for (int w2 = 0; w2 < 4; w2++) {
        int v0 = wt[w2][0], v1 = wt[w2][1], v2 = wt[w2][2], v3 = wt[w2][3];
        if (w2 < wid) { wb0 += v0; wb1 += v1; wb2 += v2; wb3 += v3; }
        to0 += v0; to1 += v1; to2 += v2; to3 += v3;
    }
    const int fb0 = 0, fb1 = to0, fb2 = to0 + to1, fb3 = to0 + to1 + to2;
    if (bid == 0 && t == 0) {
        famLoHi[0] = fb0; famLoHi[1] = fb1; famLoHi[2] = fb2; famLoHi[3] = fb3;
        famLoHi[4] = fb1; famLoHi[5] = fb2; famLoHi[6] = fb3; famLoHi[7] = fb3 + to3;
        counters[0] = 0;   // re-armed every call
    }
    int b0 = fb0 + wb0 + (i0 - lc0);
    int b1 = fb1 + wb1 + (i1 - lc1);
    int b2 = fb2 + wb2 + (i2 - lc2);
    int b3 = fb3 + wb3 + (i3 - lc3);
#pragma unroll
    for (int j = 0; j < 32; j++) {
        int f = (int)((lfp >> (2 * j)) & 3ull);
        int pos = (f == 0) ? b0 : ((f == 1) ? b1 : ((f == 2) ? b2 : b3));
        if (bid == 0) famSorted[pos] = (unsigned char)f;
        if (t == bid) posL[j] = pos;
        b0 += (f == 0); b1 += (f == 1); b2 += (f == 2); b3 += (f == 3);
    }
    __syncthreads();
#pragma unroll
    for (int rep = 0; rep < 8; rep++) {
        int rl = rep * 4 + wid;
        float x = emb[(size_t)(bid * 32 + rl) * 64 + lane];
        float ss = x * x;
#pragma unroll
        for (int o = 32; o > 0; o >>= 1) ss += __shfl_xor(ss, o, 64);
        unsigned short h = f2bf_rne(x / fmaxf(sqrtf(ss), 1e-12f));
        int pos = posL[rl];
        size_t idx = (size_t)(pos >> 4) * 1024 + (size_t)(lane >> 3) * 128 +
                     (size_t)(pos & 15) * 8 + (lane & 7);
        pack[idx] = (short)h;
    }
}

// ---------------- K2: LDS-staged bf16 MFMA GEMM + lane-local min/max ----------------
// 1D grid 2048, XCD-aware decode: r=bid&7 (round-robin XCD), colBlock=r*8+(q&7),
// rowBlock=q>>3 -> all 32 blocks of a colBlock land on one XCD (B chunk fetched
// into one L2, multicast). Chunk = 128 cols = 16KB LDS -> VGPR-bound 5 blocks/CU
// (20 waves/CU, +25% vs R15). Inner loop body identical to R11/R15 (proven).
__global__ __launch_bounds__(256) void gemm_minmax_kernel(
    const short* __restrict__ pack,
    const unsigned char* __restrict__ famSorted, const int* __restrict__ famLoHi,
    float* __restrict__ pMin, float* __restrict__ pMax, int B) {
    __shared__ short ldsB[8192];   // 16 KB

    const int lane = threadIdx.x & 63;
    const int wid  = threadIdx.x >> 6;
    const int g = lane >> 4;
    const int c = lane & 15;
    const int bid = blockIdx.x;
    const int r = bid & 7, q = bid >> 3;
    const int colBlock = r * 8 + (q & 7);   // 0..63, constant-XCD per colBlock
    const int rowBlock = q >> 3;            // 0..31
    const int rowBase = rowBlock * 256 + wid * 64;
    const int aStrip0 = rowBase >> 4;
    const int jChunk0 = colBlock * 128;
    const int jStrip0 = jChunk0 >> 4;

    // A (row) fragments first (loads in flight during staging issue).
    bf16x8 aH[4][2];
#pragma unroll
    for (int s = 0; s < 4; s++) {
        const short* pA = pack + (size_t)(aStrip0 + s) * 1024;
        aH[s][0] = *(const bf16x8*)(pA + lane * 8);
        aH[s][1] = *(const bf16x8*)(pA + 512 + lane * 8);
    }

    // Stage B chunk: 16 KB linear; each wave 4 KB = 4 x 1KB global_load_lds.
    {
        const char* src = (const char*)(pack + (size_t)jStrip0 * 1024);
#pragma unroll
        for (int i = 0; i < 4; i++) {
            int off = wid * 4096 + i * 1024;
            __builtin_amdgcn_global_load_lds((gp_t)(src + off + lane * 16),
                                             (lp_t)((char*)ldsB + off), 16, 0, 0);
        }
    }

    // Per-strip family classification (rows sorted -> piecewise constant).
    int sLo[4], sHi[4], sUni[4];
#pragma unroll
    for (int s = 0; s < 4; s++) {
        int f0  = famSorted[rowBase + s * 16];
        int f15 = famSorted[rowBase + s * 16 + 15];
        sUni[s] = __builtin_amdgcn_readfirstlane((f0 == f15) ? 1 : 0);
        sLo[s]  = __builtin_amdgcn_readfirstlane(famLoHi[f0]);
        sHi[s]  = __builtin_amdgcn_readfirstlane(famLoHi[4 + f0]);
    }

    const f32x4 zq = {0.f, 0.f, 0.f, 0.f};
    float mn[4] = {1e30f, 1e30f, 1e30f, 1e30f};
    float mx[4] = {-1e30f, -1e30f, -1e30f, -1e30f};

    __syncthreads();   // staging complete (vmcnt drained before barrier)

#pragma unroll
    for (int jp = 0; jp < NPAIR; jp++) {
        const int j0 = jChunk0 + jp * 32;
        const short* pB0 = ldsB + (size_t)(2 * jp) * 1024;
        const short* pB1 = pB0 + 1024;
        bf16x8 b0h0 = *(const bf16x8*)(pB0 + lane * 8);
        bf16x8 b0h1 = *(const bf16x8*)(pB0 + 512 + lane * 8);
        bf16x8 b1h0 = *(const bf16x8*)(pB1 + lane * 8);
        bf16x8 b1h1 = *(const bf16x8*)(pB1 + 512 + lane * 8);

#pragma unroll
        for (int s = 0; s < 4; s++) {
            // swapped operands: D[j][i], j=(g,reg) cols, i=lane&15 row
            f32x4 accA, accB;
            accA = __builtin_amdgcn_mfma_f32_16x16x32_bf16(b0h0, aH[s][0], zq, 0, 0, 0);
            accB = __builtin_amdgcn_mfma_f32_16x16x32_bf16(b1h0, aH[s][0], zq, 0, 0, 0);
            accA = __builtin_amdgcn_mfma_f32_16x16x32_bf16(b0h1, aH[s][1], accA, 0, 0, 0);
            accB = __builtin_amdgcn_mfma_f32_16x16x32_bf16(b1h1, aH[s][1], accB, 0, 0, 0);

            if (sUni[s] && j0 >= sLo[s] && j0 + 32 <= sHi[s]) {
                // both tiles fully same-family (diag dot~1 never the min)
                float a01 = fminf(accA[0], accA[1]), a23 = fminf(accA[2], accA[3]);
                float b01 = fminf(accB[0], accB[1]), b23 = fminf(accB[2], accB[3]);
                mn[s] = fminf(mn[s], fminf(fminf(a01, a23), fminf(b01, b23)));
            } else if (sUni[s] && (j0 >= sHi[s] || j0 + 32 <= sLo[s])) {
                // both tiles fully different-family
                float a01 = fmaxf(accA[0], accA[1]), a23 = fmaxf(accA[2], accA[3]);
                float b01 = fmaxf(accB[0], accB[1]), b23 = fmaxf(accB[2], accB[3]);
                mx[s] = fmaxf(mx[s], fmaxf(fmaxf(a01, a23), fmaxf(b01, b23)));
            } else {
                // rare: pair spans a family boundary -> per-element compare
                int fi = famSorted[rowBase + s * 16 + c];   // this lane's row family
                unsigned fjA = *(const unsigned*)(famSorted + j0 + g * 4);
                unsigned fjB = *(const unsigned*)(famSorted + j0 + 16 + g * 4);
#pragma unroll
                for (int r2 = 0; r2 < 4; r2++) {
                    bool sameA = ((int)((fjA >> (8 * r2)) & 255u) == fi);
                    bool sameB = ((int)((fjB >> (8 * r2)) & 255u) == fi);
                    mn[s] = fminf(mn[s], sameA ? accA[r2] : 1e30f);
                    mx[s] = fmaxf(mx[s], sameA ? -1e30f : accA[r2]);
                    mn[s] = fminf(mn[s], sameB ? accB[r2] : 1e30f);
                    mx[s] = fmaxf(mx[s], sameB ? -1e30f : accB[r2]);
                }
            }
        }
    }

    // Reduce across the 4 g-groups (lanes c, c+16, c+32, c+48): 2 shfl rounds.
#pragma unroll
    for (int s = 0; s < 4; s++) {
        float mnv = mn[s], mxv = mx[s];
        mnv = fminf(mnv, __shfl_xor(mnv, 16, 64));
        mxv = fmaxf(mxv, __shfl_xor(mxv, 16, 64));
        mnv = fminf(mnv, __shfl_xor(mnv, 32, 64));
        mxv = fmaxf(mxv, __shfl_xor(mxv, 32, 64));
        if (g == 0) {
            int row = rowBase + s * 16 + c;  // sorted-row index; 16-lane coalesced
            pMin[(size_t)colBlock * B + row] = mnv;
            pMax[(size_t)colBlock * B + row] = mxv;
        }
    }
}

// ---------------- K3: per-row combine + partial sums + last-block finalize ----------------
__global__ __launch_bounds__(256) void rowloss_final_kernel(const float* __restrict__ pMin,
                                                            const float* __restrict__ pMax,
                                                            float* __restrict__ partial,
                                                            unsigned* __restrict__ counter,
                                                            float* __restrict__ out, int B) {
    const int nb = B / 256;  // 32 blocks
    const int row = blockIdx.x * 256 + threadIdx.x;
    float mn = 1e30f, mx = -1e30f;
#pragma unroll 8
    for (int cn = 0; cn < NJ; cn++) {
        mn = fminf(mn, pMin[(size_t)cn * B + row]);
        mx = fmaxf(mx, pMax[(size_t)cn * B + row]);
    }
    float sum = 0.f, cnt = 0.f;
    if (mn < 1e29f && mx > -1e29f) {  // has same && has diff
        sum = fmaxf(mx - mn + MARGIN, 0.f);  // relu(d_pos - d_neg + margin)
        cnt = 1.f;
    }
#pragma unroll
    for (int o = 32; o > 0; o >>= 1) {
        sum += __shfl_xor(sum, o, 64);
        cnt += __shfl_xor(cnt, o, 64);
    }
    __shared__ float sS[4], sC[4];
    const int lane = threadIdx.x & 63, w = threadIdx.x >> 6;
    if (lane == 0) { sS[w] = sum; sC[w] = cnt; }
    __syncthreads();
    if (threadIdx.x == 0) {
        partial[blockIdx.x]      = sS[0] + sS[1] + sS[2] + sS[3];
        partial[64 + blockIdx.x] = sC[0] + sC[1] + sC[2] + sC[3];
        __threadfence();
        unsigned done = atomicAdd(counter, 1u);
        if (done == (unsigned)(nb - 1)) {   // last block finalizes
            __threadfence();
            float S = 0.f, C = 0.f;
            for (int i = 0; i < nb; i++) { S += partial[i]; C += partial[64 + i]; }
            out[0] = S / fmaxf(C, 1.f);
        }
    }
}

extern "C" void kernel_launch(void* const* d_in, const int* in_sizes, int n_in,
                              void* d_out, int out_size, void* d_ws, size_t ws_size,
                              hipStream_t stream) {
    const float* emb    = (const float*)d_in[0];
    const int*   labels = (const int*)d_in[1];
    const int B = in_sizes[1];  // 8192, D == 64

    char* base = (char*)d_ws;
    size_t off = 0;
    auto alloc = [&](size_t bytes) -> char* {
        char* p = base + off;
        off = (off + bytes + 255) & ~(size_t)255;
        return p;
    };
    unsigned char* famSorted = (unsigned char*)alloc((size_t)B);
    int*           famLoHi   = (int*)alloc(64);
    unsigned*      counters  = (unsigned*)alloc(64);
    short*         pack      = (short*)alloc((size_t)B * 64 * 2);  // hi-only, 1MB
    float*         pMin      = (float*)alloc((size_t)NJ * B * 4);
    float*         pMax      = (float*)alloc((size_t)NJ * B * 4);
    float*         partial   = (float*)alloc(128 * 4);

    prep_kernel<<<256, 256, 0, stream>>>(emb, labels, famSorted, famLoHi,
                                         counters, pack, B);
    gemm_minmax_kernel<<<2048, 256, 0, stream>>>(pack, famSorted, famLoHi,
                                                 pMin, pMax, B);
    rowloss_final_kernel<<<B / 256, 256, 0, stream>>>(pMin, pMax, partial, counters,
                                                      (float*)d_out, B);
}

// Round 18
// 31.966 us; speedup vs baseline: 1.3652x; 1.1044x over previous
//
#include <hip/hip_runtime.h>
#include <math.h>

#define MARGIN 0.3f
#define NJ 32        // column chunks; chunk = 256 cols = 8 pairs of 16x2
#define NPAIR 8      // compile-time: (8192/NJ)/32

typedef short bf16x8 __attribute__((ext_vector_type(8)));
typedef float f32x4 __attribute__((ext_vector_type(4)));
typedef unsigned int u32;
typedef const __attribute__((address_space(1))) u32* gp_t;
typedef __attribute__((address_space(3))) u32* lp_t;

__device__ __forceinline__ unsigned short f2bf_rne(float x) {
    unsigned b = __float_as_uint(x);
    unsigned r = b + 0x7FFFu + ((b >> 16) & 1u);
    return (unsigned short)(r >> 16);
}
// family table {0,1,2,1,3,3} packed 2 bits/entry
__device__ __forceinline__ int fam_of(int lbl) { return (0xF64 >> (2 * lbl)) & 3; }

// ---------------- K1: fused sort + normalize + pack (verified R14/R15) ----------------
// 256 blocks x 256 threads. EVERY block redundantly computes the counting-sort
// prefix structure (deterministic, identical) -> no inter-block dependency.
// Thread t covers labels [t*32, t*32+32); block b packs rows [b*32, b*32+32).
// pack layout: idx = strip*1024 + (k>>3)*128 + (pos&15)*8 + (k&7)  [R2-verified]
__global__ __launch_bounds__(256) void prep_kernel(
    const float* __restrict__ emb, const int* __restrict__ labels,
    unsigned char* __restrict__ famSorted, int* __restrict__ famLoHi,
    unsigned* __restrict__ counters, short* __restrict__ pack, int B) {
    __shared__ int wt[4][4];
    __shared__ int posL[32];
    const int t = threadIdx.x, lane = t & 63, wid = t >> 6, bid = blockIdx.x;

    // pass 1: per-thread family counts; fams packed 2b into a u64 (no reload)
    unsigned long long lfp = 0ull;
    int lc0 = 0, lc1 = 0, lc2 = 0, lc3 = 0;
#pragma unroll
    for (int j = 0; j < 32; j++) {
        int f = fam_of(labels[t * 32 + j]);
        lfp |= (unsigned long long)f << (2 * j);
        lc0 += (f == 0); lc1 += (f == 1); lc2 += (f == 2); lc3 += (f == 3);
    }
    // wave inclusive scans (4 families)
    int i0 = lc0, i1 = lc1, i2 = lc2, i3 = lc3;
#pragma unroll
    for (int o = 1; o < 64; o <<= 1) {
        int u0 = __shfl_up(i0, o, 64), u1 = __shfl_up(i1, o, 64);
        int u2 = __shfl_up(i2, o, 64), u3 = __shfl_up(i3, o, 64);
        if (lane >= o) { i0 += u0; i1 += u1; i2 += u2; i3 += u3; }
    }
    if (lane == 63) { wt[wid][0] = i0; wt[wid][1] = i1; wt[wid][2] = i2; wt[wid][3] = i3; }
    __syncthreads();
    int wb0 = 0, wb1 = 0, wb2 = 0, wb3 = 0, to0 = 0, to1 = 0, to2 = 0, to3 = 0;
#pragma unroll
    for (int w2 = 0; w2 < 4; w2++) {
        int v0 = wt[w2][0], v1 = wt[w2][1], v2 = wt[w2][2], v3 = wt[w2][3];
        if (w2 < wid) { wb0 += v0; wb1 += v1; wb2 += v2; wb3 += v3; }
        to0 += v0; to1 += v1; to2 += v2; to3 += v3;
    }
    const int fb0 = 0, fb1 = to0, fb2 = to0 + to1, fb3 = to0 + to1 + to2;
    if (bid == 0 && t == 0) {
        famLoHi[0] = fb0; famLoHi[1] = fb1; famLoHi[2] = fb2; famLoHi[3] = fb3;
        famLoHi[4] = fb1; famLoHi[5] = fb2; famLoHi[6] = fb3; famLoHi[7] = fb3 + to3;
        counters[0] = 0;   // re-armed every call (rowloss_final last-block detect)
    }
    int b0 = fb0 + wb0 + (i0 - lc0);
    int b1 = fb1 + wb1 + (i1 - lc1);
    int b2 = fb2 + wb2 + (i2 - lc2);
    int b3 = fb3 + wb3 + (i3 - lc3);
    // pass 2: positions; block 0 writes famSorted; thread t==bid keeps its rows
#pragma unroll
    for (int j = 0; j < 32; j++) {
        int f = (int)((lfp >> (2 * j)) & 3ull);
        int pos = (f == 0) ? b0 : ((f == 1) ? b1 : ((f == 2) ? b2 : b3));
        if (bid == 0) famSorted[pos] = (unsigned char)f;
        if (t == bid) posL[j] = pos;
        b0 += (f == 0); b1 += (f == 1); b2 += (f == 2); b3 += (f == 3);
    }
    __syncthreads();
    // normalize + scatter rows [bid*32, bid*32+32): wave-per-row, 8 reps
#pragma unroll
    for (int rep = 0; rep < 8; rep++) {
        int rl = rep * 4 + wid;
        float x = emb[(size_t)(bid * 32 + rl) * 64 + lane];
        float ss = x * x;
#pragma unroll
        for (int o = 32; o > 0; o >>= 1) ss += __shfl_xor(ss, o, 64);
        unsigned short h = f2bf_rne(x / fmaxf(sqrtf(ss), 1e-12f));
        int pos = posL[rl];
        size_t idx = (size_t)(pos >> 4) * 1024 + (size_t)(lane >> 3) * 128 +
                     (size_t)(pos & 15) * 8 + (lane & 7);
        pack[idx] = (short)h;
    }
}

// ---------------- K2: LDS-staged bf16 MFMA GEMM + lane-local min/max (R11 exact) ----------------
__global__ __launch_bounds__(256) void gemm_minmax_kernel(
    const short* __restrict__ pack,
    const unsigned char* __restrict__ famSorted, const int* __restrict__ famLoHi,
    float* __restrict__ pMin, float* __restrict__ pMax, int B) {
    __shared__ short ldsB[16384];   // 32 KB

    const int lane = threadIdx.x & 63;
    const int wid  = threadIdx.x >> 6;
    const int g = lane >> 4;
    const int c = lane & 15;
    const int rowBase = blockIdx.x * 256 + wid * 64;
    const int aStrip0 = rowBase >> 4;
    const int jChunk0 = blockIdx.y * 256;
    const int jStrip0 = jChunk0 >> 4;

    // A (row) fragments first (loads in flight during staging issue).
    bf16x8 aH[4][2];
#pragma unroll
    for (int s = 0; s < 4; s++) {
        const short* pA = pack + (size_t)(aStrip0 + s) * 1024;
        aH[s][0] = *(const bf16x8*)(pA + lane * 8);
        aH[s][1] = *(const bf16x8*)(pA + 512 + lane * 8);
    }

    // Stage B chunk: 32 KB linear; each wave 8 KB = 8 x 1KB global_load_lds.
    {
        const char* src = (const char*)(pack + (size_t)jStrip0 * 1024);
#pragma unroll
        for (int i = 0; i < 8; i++) {
            int off = wid * 8192 + i * 1024;
            __builtin_amdgcn_global_load_lds((gp_t)(src + off + lane * 16),
                                             (lp_t)((char*)ldsB + off), 16, 0, 0);
        }
    }

    // Per-strip family classification (rows sorted -> piecewise constant).
    int sLo[4], sHi[4], sUni[4];
#pragma unroll
    for (int s = 0; s < 4; s++) {
        int f0  = famSorted[rowBase + s * 16];
        int f15 = famSorted[rowBase + s * 16 + 15];
        sUni[s] = __builtin_amdgcn_readfirstlane((f0 == f15) ? 1 : 0);
        sLo[s]  = __builtin_amdgcn_readfirstlane(famLoHi[f0]);
        sHi[s]  = __builtin_amdgcn_readfirstlane(famLoHi[4 + f0]);
    }

    const f32x4 zq = {0.f, 0.f, 0.f, 0.f};
    float mn[4] = {1e30f, 1e30f, 1e30f, 1e30f};
    float mx[4] = {-1e30f, -1e30f, -1e30f, -1e30f};

    __syncthreads();   // staging complete (vmcnt drained before barrier)

#pragma unroll
    for (int jp = 0; jp < NPAIR; jp++) {
        const int j0 = jChunk0 + jp * 32;
        const short* pB0 = ldsB + (size_t)(2 * jp) * 1024;
        const short* pB1 = pB0 + 1024;
        bf16x8 b0h0 = *(const bf16x8*)(pB0 + lane * 8);
        bf16x8 b0h1 = *(const bf16x8*)(pB0 + 512 + lane * 8);
        bf16x8 b1h0 = *(const bf16x8*)(pB1 + lane * 8);
        bf16x8 b1h1 = *(const bf16x8*)(pB1 + 512 + lane * 8);

#pragma unroll
        for (int s = 0; s < 4; s++) {
            // swapped operands: D[j][i], j=(g,reg) cols, i=lane&15 row
            f32x4 accA, accB;
            accA = __builtin_amdgcn_mfma_f32_16x16x32_bf16(b0h0, aH[s][0], zq, 0, 0, 0);
            accB = __builtin_amdgcn_mfma_f32_16x16x32_bf16(b1h0, aH[s][0], zq, 0, 0, 0);
            accA = __builtin_amdgcn_mfma_f32_16x16x32_bf16(b0h1, aH[s][1], accA, 0, 0, 0);
            accB = __builtin_amdgcn_mfma_f32_16x16x32_bf16(b1h1, aH[s][1], accB, 0, 0, 0);

            if (sUni[s] && j0 >= sLo[s] && j0 + 32 <= sHi[s]) {
                // both tiles fully same-family (diag dot~1 never the min)
                float a01 = fminf(accA[0], accA[1]), a23 = fminf(accA[2], accA[3]);
                float b01 = fminf(accB[0], accB[1]), b23 = fminf(accB[2], accB[3]);
                mn[s] = fminf(mn[s], fminf(fminf(a01, a23), fminf(b01, b23)));
            } else if (sUni[s] && (j0 >= sHi[s] || j0 + 32 <= sLo[s])) {
                // both tiles fully different-family
                float a01 = fmaxf(accA[0], accA[1]), a23 = fmaxf(accA[2], accA[3]);
                float b01 = fmaxf(accB[0], accB[1]), b23 = fmaxf(accB[2], accB[3]);
                mx[s] = fmaxf(mx[s], fmaxf(fmaxf(a01, a23), fmaxf(b01, b23)));
            } else {
                // rare: pair spans a family boundary -> per-element compare
                int fi = famSorted[rowBase + s * 16 + c];   // this lane's row family
                unsigned fjA = *(const unsigned*)(famSorted + j0 + g * 4);
                unsigned fjB = *(const unsigned*)(famSorted + j0 + 16 + g * 4);
#pragma unroll
                for (int r = 0; r < 4; r++) {
                    bool sameA = ((int)((fjA >> (8 * r)) & 255u) == fi);
                    bool sameB = ((int)((fjB >> (8 * r)) & 255u) == fi);
                    mn[s] = fminf(mn[s], sameA ? accA[r] : 1e30f);
                    mx[s] = fmaxf(mx[s], sameA ? -1e30f : accA[r]);
                    mn[s] = fminf(mn[s], sameB ? accB[r] : 1e30f);
                    mx[s] = fmaxf(mx[s], sameB ? -1e30f : accB[r]);
                }
            }
        }
    }

    // Reduce across the 4 g-groups (lanes c, c+16, c+32, c+48): 2 shfl rounds.
#pragma unroll
    for (int s = 0; s < 4; s++) {
        float mnv = mn[s], mxv = mx[s];
        mnv = fminf(mnv, __shfl_xor(mnv, 16, 64));
        mxv = fmaxf(mxv, __shfl_xor(mxv, 16, 64));
        mnv = fminf(mnv, __shfl_xor(mnv, 32, 64));
        mxv = fmaxf(mxv, __shfl_xor(mxv, 32, 64));
        if (g == 0) {
            int row = rowBase + s * 16 + c;  // sorted-row index; 16-lane coalesced
            pMin[(size_t)blockIdx.y * B + row] = mnv;
            pMax[(size_t)blockIdx.y * B + row] = mxv;
        }
    }
}

// ---------------- K3: per-row combine + partial sums + last-block finalize (R11 exact) ----------------
__global__ __launch_bounds__(256) void rowloss_final_kernel(const float* __restrict__ pMin,
                                                            const float* __restrict__ pMax,
                                                            float* __restrict__ partial,
                                                            unsigned* __restrict__ counter,
                                                            float* __restrict__ out, int B) {
    const int nb = B / 256;  // 32 blocks
    const int row = blockIdx.x * 256 + threadIdx.x;
    float mn = 1e30f, mx = -1e30f;
#pragma unroll 8
    for (int cn = 0; cn < NJ; cn++) {
        mn = fminf(mn, pMin[(size_t)cn * B + row]);
        mx = fmaxf(mx, pMax[(size_t)cn * B + row]);
    }
    float sum = 0.f, cnt = 0.f;
    if (mn < 1e29f && mx > -1e29f) {  // has same && has diff
        sum = fmaxf(mx - mn + MARGIN, 0.f);  // relu(d_pos - d_neg + margin)
        cnt = 1.f;
    }
#pragma unroll
    for (int o = 32; o > 0; o >>= 1) {
        sum += __shfl_xor(sum, o, 64);
        cnt += __shfl_xor(cnt, o, 64);
    }
    __shared__ float sS[4], sC[4];
    const int lane = threadIdx.x & 63, w = threadIdx.x >> 6;
    if (lane == 0) { sS[w] = sum; sC[w] = cnt; }
    __syncthreads();
    if (threadIdx.x == 0) {
        partial[blockIdx.x]      = sS[0] + sS[1] + sS[2] + sS[3];
        partial[64 + blockIdx.x] = sC[0] + sC[1] + sC[2] + sC[3];
        __threadfence();
        unsigned done = atomicAdd(counter, 1u);
        if (done == (unsigned)(nb - 1)) {   // last block finalizes
            __threadfence();
            float S = 0.f, C = 0.f;
            for (int i = 0; i < nb; i++) { S += partial[i]; C += partial[64 + i]; }
            out[0] = S / fmaxf(C, 1.f);
        }
    }
}

extern "C" void kernel_launch(void* const* d_in, const int* in_sizes, int n_in,
                              void* d_out, int out_size, void* d_ws, size_t ws_size,
                              hipStream_t stream) {
    const float* emb    = (const float*)d_in[0];
    const int*   labels = (const int*)d_in[1];
    const int B = in_sizes[1];  // 8192, D == 64

    char* base = (char*)d_ws;
    size_t off = 0;
    auto alloc = [&](size_t bytes) -> char* {
        char* p = base + off;
        off = (off + bytes + 255) & ~(size_t)255;
        return p;
    };
    unsigned char* famSorted = (unsigned char*)alloc((size_t)B);
    int*           famLoHi   = (int*)alloc(64);
    unsigned*      counters  = (unsigned*)alloc(64);
    short*         pack      = (short*)alloc((size_t)B * 64 * 2);  // hi-only, 1MB
    float*         pMin      = (float*)alloc((size_t)NJ * B * 4);
    float*         pMax      = (float*)alloc((size_t)NJ * B * 4);
    float*         partial   = (float*)alloc(128 * 4);

    prep_kernel<<<256, 256, 0, stream>>>(emb, labels, famSorted, famLoHi,
                                         counters, pack, B);
    dim3 g3(B / 256, NJ);
    gemm_minmax_kernel<<<g3, 256, 0, stream>>>(pack, famSorted, famLoHi, pMin, pMax, B);
    rowloss_final_kernel<<<B / 256, 256, 0, stream>>>(pMin, pMax, partial, counters,
                                                      (float*)d_out, B);
}